// Round 1
// baseline (263.740 us; speedup 1.0000x reference)
//
#include <hip/hip_runtime.h>
#include <cmath>

// Problem constants (fixed by setup_inputs): B=16, C=256, W=H=112, L=8.
#define WDIM 112
#define HDIM 112
#define TI   28          // output rows per block tile (112 = 4*28)
#define LDSW 120         // padded LDS row stride in floats (116 used, 16B-aligned rows)
#define XROWS (TI + 8)   // x tile rows incl. halo 4 each side
#define VROWS (TI + 4)   // v1 tile rows incl. halo 2 each side

// ---------------------------------------------------------------------------
// Kernel 1: pdf_mean[i][j] = mean_l exp(-0.5*||(pos-loc_l)/scal_l||^2
//                                       - sum(log scal_l) - log(2pi))
// ---------------------------------------------------------------------------
__global__ __launch_bounds__(256) void pdf_kernel(
    const float* __restrict__ loc,   // (L,2)
    const float* __restrict__ scal,  // (L,2)
    const float* __restrict__ pscal, // (1,)
    float* __restrict__ pdfm,        // (112*112,)
    int L) {
  int idx = blockIdx.x * 256 + threadIdx.x;
  if (idx >= WDIM * HDIM) return;
  int i = idx / HDIM;
  int j = idx - i * HDIM;
  float ps = pscal[0];
  float px = (float)i * ps;
  float py = (float)j * ps;
  const float LOG2PI = 1.8378770664093453f;  // log(2*pi)
  float s = 0.f;
  for (int l = 0; l < L; ++l) {
    float lx = loc[2 * l + 0], ly = loc[2 * l + 1];
    float sx = scal[2 * l + 0], sy = scal[2 * l + 1];
    float dx = (px - lx) / sx;
    float dy = (py - ly) / sy;
    float logp = -0.5f * (dx * dx + dy * dy) - (logf(sx) + logf(sy)) - LOG2PI;
    s += expf(logp);
  }
  pdfm[idx] = s / (float)L;
}

// ---------------------------------------------------------------------------
// Kernel 2: fused depthwise conv -> relu -> depthwise conv -> *pdf -> +x
// One block per (b, c, row-tile). 256 threads.
// ---------------------------------------------------------------------------
__global__ __launch_bounds__(256) void fused_kernel(
    const float* __restrict__ x,
    const float* __restrict__ w1,  // (C,25)
    const float* __restrict__ b1,  // (C,)
    const float* __restrict__ w2,  // (C,25)
    const float* __restrict__ b2,  // (C,)
    const float* __restrict__ pdfm,
    float* __restrict__ out,
    int C) {
  __shared__ float xt[XROWS * LDSW];
  __shared__ float vt[VROWS * LDSW];

  const int tid = threadIdx.x;
  const int tile = blockIdx.x;          // 0..3
  const int c = blockIdx.y;
  const int b = blockIdx.z;
  const int i0 = tile * TI;

  const size_t plane = (size_t)(b * C + c) * (WDIM * HDIM);
  const float* xp = x + plane;
  float* op = out + plane;

  // Uniform weight loads (scalar-load friendly).
  float w1r[25], w2r[25];
#pragma unroll
  for (int k = 0; k < 25; ++k) w1r[k] = w1[c * 25 + k];
#pragma unroll
  for (int k = 0; k < 25; ++k) w2r[k] = w2[c * 25 + k];
  const float b1v = b1[c];
  const float b2v = b2[c];

  // ---- Phase 1: stage x tile into LDS (zero-padded halo) ----
  // xt row r  <-> global row gi = i0 - 4 + r
  // xt col jj <-> global col j  = jj - 2   (jj in [0,116); 116..119 zero pad)
  for (int idx = tid; idx < XROWS * LDSW; idx += 256) {
    int r = idx / LDSW;
    int jj = idx - r * LDSW;
    int gi = i0 - 4 + r;
    int j = jj - 2;
    float v = 0.f;
    if (gi >= 0 && gi < WDIM && j >= 0 && j < HDIM && jj < 116)
      v = xp[gi * HDIM + j];
    xt[idx] = v;
  }
  // Zero v1 border columns (conv2 padding): jj in {0,1,114,115} for all rows,
  // plus the unread tail (116..119) left untouched (never read).
  for (int r = tid; r < VROWS; r += 256) {
    vt[r * LDSW + 0] = 0.f;
    vt[r * LDSW + 1] = 0.f;
    vt[r * LDSW + 114] = 0.f;
    vt[r * LDSW + 115] = 0.f;
  }
  __syncthreads();

  // ---- Phase 2: conv1 + bias + relu -> vt ----
  // vt row rr <-> global row gi = i0 - 2 + rr. Rows outside [0,112) are conv2
  // padding -> must be exactly 0 (NOT relu(b1)).
  for (int g = tid; g < VROWS * 28; g += 256) {
    int rr = g / 28;
    int cg = g - rr * 28;
    int j0 = cg * 4;  // output cols j0..j0+3
    int gi = i0 - 2 + rr;
    float acc0 = b1v, acc1 = b1v, acc2 = b1v, acc3 = b1v;
#pragma unroll
    for (int dr = 0; dr < 5; ++dr) {
      const float* row = &xt[(rr + dr) * LDSW + j0];  // 16B aligned
      float xv[8];
#pragma unroll
      for (int m = 0; m < 8; ++m) xv[m] = row[m];
#pragma unroll
      for (int dc = 0; dc < 5; ++dc) {
        float w = w1r[dr * 5 + dc];
        acc0 = fmaf(w, xv[0 + dc], acc0);
        acc1 = fmaf(w, xv[1 + dc], acc1);
        acc2 = fmaf(w, xv[2 + dc], acc2);
        acc3 = fmaf(w, xv[3 + dc], acc3);
      }
    }
    bool valid = (gi >= 0) && (gi < WDIM);
    float* vrow = &vt[rr * LDSW + j0 + 2];
    vrow[0] = valid ? fmaxf(acc0, 0.f) : 0.f;
    vrow[1] = valid ? fmaxf(acc1, 0.f) : 0.f;
    vrow[2] = valid ? fmaxf(acc2, 0.f) : 0.f;
    vrow[3] = valid ? fmaxf(acc3, 0.f) : 0.f;
  }
  __syncthreads();

  // ---- Phase 3: conv2 + bias, * pdf, + x, store ----
  for (int g = tid; g < TI * 28; g += 256) {
    int ro = g / 28;
    int cg = g - ro * 28;
    int j0 = cg * 4;
    int gi = i0 + ro;
    float acc0 = b2v, acc1 = b2v, acc2 = b2v, acc3 = b2v;
#pragma unroll
    for (int dr = 0; dr < 5; ++dr) {
      const float* row = &vt[(ro + dr) * LDSW + j0];  // 16B aligned
      float vv[8];
#pragma unroll
      for (int m = 0; m < 8; ++m) vv[m] = row[m];
#pragma unroll
      for (int dc = 0; dc < 5; ++dc) {
        float w = w2r[dr * 5 + dc];
        acc0 = fmaf(w, vv[0 + dc], acc0);
        acc1 = fmaf(w, vv[1 + dc], acc1);
        acc2 = fmaf(w, vv[2 + dc], acc2);
        acc3 = fmaf(w, vv[3 + dc], acc3);
      }
    }
    const float4 pv = *reinterpret_cast<const float4*>(&pdfm[gi * HDIM + j0]);
    const float* xc = &xt[(ro + 4) * LDSW + j0 + 2];  // residual x (center)
    float4 o;
    o.x = xc[0] + acc0 * pv.x;
    o.y = xc[1] + acc1 * pv.y;
    o.z = xc[2] + acc2 * pv.z;
    o.w = xc[3] + acc3 * pv.w;
    *reinterpret_cast<float4*>(&op[gi * HDIM + j0]) = o;
  }
}

extern "C" void kernel_launch(void* const* d_in, const int* in_sizes, int n_in,
                              void* d_out, int out_size, void* d_ws, size_t ws_size,
                              hipStream_t stream) {
  const float* x    = (const float*)d_in[0];
  const float* w1   = (const float*)d_in[1];
  const float* b1   = (const float*)d_in[2];
  const float* w2   = (const float*)d_in[3];
  const float* b2   = (const float*)d_in[4];
  const float* loc  = (const float*)d_in[5];
  const float* scal = (const float*)d_in[6];
  const float* ps   = (const float*)d_in[7];
  float* out = (float*)d_out;
  float* pdfm = (float*)d_ws;  // 112*112 floats = 50 KB scratch

  const int C = in_sizes[2];                         // 256
  const int B = in_sizes[0] / (C * WDIM * HDIM);     // 16
  const int L = in_sizes[5] / 2;                     // 8

  hipLaunchKernelGGL(pdf_kernel, dim3((WDIM * HDIM + 255) / 256), dim3(256), 0,
                     stream, loc, scal, ps, pdfm, L);
  dim3 grid(WDIM / TI, C, B);
  hipLaunchKernelGGL(fused_kernel, grid, dim3(256), 0, stream, x, w1, b1, w2,
                     b2, pdfm, out, C);
}

// Round 2
// 220.140 us; speedup vs baseline: 1.1981x; 1.1981x over previous
//
#include <hip/hip_runtime.h>
#include <cmath>

// Problem constants (fixed by setup_inputs): B=16, C=256, W=H=112, L=8.
#define WDIM 112
#define HDIM 112
#define TROWS 56   // output rows per tile (2 tiles cover 112)

// ---------------------------------------------------------------------------
// Kernel 1: pdf_mean[i][j] (112x112, 50KB -> L2-resident)
// ---------------------------------------------------------------------------
__global__ __launch_bounds__(256) void pdf_kernel(
    const float* __restrict__ loc,   // (L,2)
    const float* __restrict__ scal,  // (L,2)
    const float* __restrict__ pscal, // (1,)
    float* __restrict__ pdfm,        // (112*112,)
    int L) {
  int idx = blockIdx.x * 256 + threadIdx.x;
  if (idx >= WDIM * HDIM) return;
  int i = idx / HDIM;
  int j = idx - i * HDIM;
  float ps = pscal[0];
  float px = (float)i * ps;
  float py = (float)j * ps;
  const float LOG2PI = 1.8378770664093453f;  // log(2*pi)
  float s = 0.f;
  for (int l = 0; l < L; ++l) {
    float lx = loc[2 * l + 0], ly = loc[2 * l + 1];
    float sx = scal[2 * l + 0], sy = scal[2 * l + 1];
    float dx = (px - lx) / sx;
    float dy = (py - ly) / sy;
    float logp = -0.5f * (dx * dx + dy * dy) - (logf(sx) + logf(sy)) - LOG2PI;
    s += expf(logp);
  }
  pdfm[idx] = s / (float)L;
}

// ---------------------------------------------------------------------------
// Kernel 2: register-streaming fused depthwise conv->relu->conv->*pdf->+x.
// No LDS, no barriers. Block = 256 threads = 8 groups of 32 lanes.
// Each group: one (b,c) plane row-tile; lane owns 4 cols (lanes 28..31 idle).
// Block is a single channel c (blockIdx.y) -> weights are wave-uniform SGPRs.
//
// Incremental streaming over x rows s:
//   x row s -> contributes to partial v rows s-2..s+2 (ring of 5, 8 cols incl
//   +-2 halo, computed redundantly per lane -> no cross-lane exchange).
//   v row t=s-2 completes -> bias+relu -> contributes to partial out rows
//   t-2..t+2 (ring of 5, 4 cols).
//   out row g=s-4 completes -> +b2, *pdf, +x, store.
// Ring indices are static: s_idx%5 == u via chunk-of-5 full unroll.
// ---------------------------------------------------------------------------
__global__ __launch_bounds__(256, 4) void fused_kernel(
    const float* __restrict__ x,
    const float* __restrict__ w1,  // (C,25)
    const float* __restrict__ b1,  // (C,)
    const float* __restrict__ w2,  // (C,25)
    const float* __restrict__ b2,  // (C,)
    const float* __restrict__ pdfm,
    float* __restrict__ out,
    int C) {
  const int tid = threadIdx.x;
  const int lane = tid & 31;
  const int group = tid >> 5;              // 0..7
  const int tile = blockIdx.x;             // 0..1
  const int c = blockIdx.y;                // channel (uniform per block)
  const int b = blockIdx.z * 8 + group;    // batch
  const int g0 = tile * TROWS;
  const int j0 = lane * 4;                 // output cols j0..j0+3

  const size_t plane = (size_t)(b * C + c) * (WDIM * HDIM);
  const float* xp = x + plane;
  float* op = out + plane;

  // Uniform (per-block) weights -> scalar registers.
  float w1s[25], w2s[25];
#pragma unroll
  for (int k = 0; k < 25; ++k) w1s[k] = w1[c * 25 + k];
#pragma unroll
  for (int k = 0; k < 25; ++k) w2s[k] = w2[c * 25 + k];
  const float b1v = b1[c];
  const float b2v = b2[c];

  // Rings (all statically indexed after unroll -> registers).
  float vring[5][8];  // partial conv1 rows, cols j0-2..j0+5
  float oring[5][4];  // partial conv2 rows, cols j0..j0+3
#pragma unroll
  for (int r = 0; r < 5; ++r) {
#pragma unroll
    for (int q = 0; q < 8; ++q) vring[r][q] = 0.f;
#pragma unroll
    for (int q = 0; q < 4; ++q) oring[r][q] = 0.f;
  }

  const bool lane_a = (lane >= 1) && (lane < 28);  // load x[j0-4..j0-1]
  const bool lane_b = (lane < 28);                 // load x[j0..j0+3]
  const bool lane_c = (lane <= 26);                // load x[j0+4..j0+7]
  const int s_base = g0 - 4;

  for (int chunk = 0; chunk < 13; ++chunk) {
#pragma unroll
    for (int u = 0; u < 5; ++u) {
      const int s = s_base + chunk * 5 + u;  // current x row
      // ---- 1. load x row s (12 cols, zero-padded) ----
      float xr[12];
      const bool rv = (s >= 0) && (s < WDIM);
      float4 av = make_float4(0.f, 0.f, 0.f, 0.f);
      float4 bv = make_float4(0.f, 0.f, 0.f, 0.f);
      float4 cv = make_float4(0.f, 0.f, 0.f, 0.f);
      if (rv && lane_a) av = *reinterpret_cast<const float4*>(xp + s * HDIM + j0 - 4);
      if (rv && lane_b) bv = *reinterpret_cast<const float4*>(xp + s * HDIM + j0);
      if (rv && lane_c) cv = *reinterpret_cast<const float4*>(xp + s * HDIM + j0 + 4);
      xr[0] = av.x; xr[1] = av.y; xr[2] = av.z; xr[3] = av.w;
      xr[4] = bv.x; xr[5] = bv.y; xr[6] = bv.z; xr[7] = bv.w;
      xr[8] = cv.x; xr[9] = cv.y; xr[10] = cv.z; xr[11] = cv.w;

      // ---- 2. recycle v slot for t = s+2 ----
#pragma unroll
      for (int q = 0; q < 8; ++q) vring[(u + 2) % 5][q] = 0.f;

      // ---- 3. conv1 contributions: x row s -> v rows s-2..s+2 ----
#pragma unroll
      for (int k = 0; k < 5; ++k) {
        const int slot = (u + 3 + k) % 5;  // v row t = s-2+k
        const int dr = 4 - k;              // s = t-2+dr
#pragma unroll
        for (int dc = 0; dc < 5; ++dc) {
          const float w = w1s[dr * 5 + dc];
#pragma unroll
          for (int cc = 0; cc < 8; ++cc)
            vring[slot][cc] = fmaf(w, xr[cc + dc], vring[slot][cc]);
        }
      }

      // ---- 4. finalize v row t = s-2 (bias+relu; zero if padding row) ----
      const int t = s - 2;
      const bool tv = (t >= 0) && (t < WDIM);
      float vcv[8];
#pragma unroll
      for (int q = 0; q < 8; ++q)
        vcv[q] = tv ? fmaxf(vring[(u + 3) % 5][q] + b1v, 0.f) : 0.f;

      // ---- 5. recycle out slot for g = s ----
#pragma unroll
      for (int q = 0; q < 4; ++q) oring[u][q] = 0.f;

      // ---- 6. conv2 contributions: v row t -> out rows t-2..t+2 ----
#pragma unroll
      for (int k = 0; k < 5; ++k) {
        const int slot = (u + 1 + k) % 5;  // out row g = s-4+k
        const int dr = 4 - k;              // t = g-2+dr
#pragma unroll
        for (int dc = 0; dc < 5; ++dc) {
          const float w = w2s[dr * 5 + dc];
#pragma unroll
          for (int co = 0; co < 4; ++co)
            oring[slot][co] = fmaf(w, vcv[co + dc], oring[slot][co]);
        }
      }

      // ---- 7. finalize out row g = s-4: +b2, *pdf, +x, store ----
      const int g = s - 4;
      if ((g >= g0) && (g < g0 + TROWS) && (lane < 28)) {
        const float4 pv = *reinterpret_cast<const float4*>(pdfm + g * HDIM + j0);
        const float4 xcv = *reinterpret_cast<const float4*>(xp + g * HDIM + j0);
        float4 o;
        o.x = xcv.x + (oring[(u + 1) % 5][0] + b2v) * pv.x;
        o.y = xcv.y + (oring[(u + 1) % 5][1] + b2v) * pv.y;
        o.z = xcv.z + (oring[(u + 1) % 5][2] + b2v) * pv.z;
        o.w = xcv.w + (oring[(u + 1) % 5][3] + b2v) * pv.w;
        *reinterpret_cast<float4*>(op + g * HDIM + j0) = o;
      }
    }
  }
}

extern "C" void kernel_launch(void* const* d_in, const int* in_sizes, int n_in,
                              void* d_out, int out_size, void* d_ws, size_t ws_size,
                              hipStream_t stream) {
  const float* x    = (const float*)d_in[0];
  const float* w1   = (const float*)d_in[1];
  const float* b1   = (const float*)d_in[2];
  const float* w2   = (const float*)d_in[3];
  const float* b2   = (const float*)d_in[4];
  const float* loc  = (const float*)d_in[5];
  const float* scal = (const float*)d_in[6];
  const float* ps   = (const float*)d_in[7];
  float* out = (float*)d_out;
  float* pdfm = (float*)d_ws;  // 112*112 floats = 50 KB scratch

  const int C = in_sizes[2];                     // 256
  const int L = in_sizes[5] / 2;                 // 8

  hipLaunchKernelGGL(pdf_kernel, dim3((WDIM * HDIM + 255) / 256), dim3(256), 0,
                     stream, loc, scal, ps, pdfm, L);
  // grid: (row-tile, channel, batch-pair-of-8); block = 8 batches x 32 lanes.
  dim3 grid(2, C, 2);
  hipLaunchKernelGGL(fused_kernel, grid, dim3(256), 0, stream, x, w1, b1, w2,
                     b2, pdfm, out, C);
}

// Round 3
// 177.034 us; speedup vs baseline: 1.4898x; 1.2435x over previous
//
#include <hip/hip_runtime.h>
#include <cmath>

// Problem constants (fixed by setup_inputs): B=16, C=256, W=H=112, L=8.
#define WDIM 112
#define HDIM 112
#define TROWS 28   // output rows per tile (4 tiles cover 112)

// ---------------------------------------------------------------------------
// Kernel 1: pdf_mean[i][j] (112x112, 50KB -> L2-resident)
// ---------------------------------------------------------------------------
__global__ __launch_bounds__(256) void pdf_kernel(
    const float* __restrict__ loc,   // (L,2)
    const float* __restrict__ scal,  // (L,2)
    const float* __restrict__ pscal, // (1,)
    float* __restrict__ pdfm,        // (112*112,)
    int L) {
  int idx = blockIdx.x * 256 + threadIdx.x;
  if (idx >= WDIM * HDIM) return;
  int i = idx / HDIM;
  int j = idx - i * HDIM;
  float ps = pscal[0];
  float px = (float)i * ps;
  float py = (float)j * ps;
  const float LOG2PI = 1.8378770664093453f;  // log(2*pi)
  float s = 0.f;
  for (int l = 0; l < L; ++l) {
    float lx = loc[2 * l + 0], ly = loc[2 * l + 1];
    float sx = scal[2 * l + 0], sy = scal[2 * l + 1];
    float dx = (px - lx) / sx;
    float dy = (py - ly) / sy;
    float logp = -0.5f * (dx * dx + dy * dy) - (logf(sx) + logf(sy)) - LOG2PI;
    s += expf(logp);
  }
  pdfm[idx] = s / (float)L;
}

// ---------------------------------------------------------------------------
// Kernel 2: register-streaming fused depthwise conv->relu->conv->*pdf->+x.
// No LDS, no barriers. Block = 256 threads = 8 groups of 32 lanes.
// Group: one (b,c) 28-row tile; lane owns 4 cols (lanes 28..31 idle/zero).
// Channel uniform per block -> weights live in SGPRs.
//
// Streaming over x rows s (40 steps, ring%5 static via chunk-of-5 unroll):
//   x row s (8 cols j0-2..j0+5) -> conv1 partial for OWN 4 cols of v rows
//   s-2..s+2 (vring, init=b1).
//   v row t=s-2 completes -> relu -> v-halo (+-2 cols) from neighbor lanes
//   via __shfl within 32-lane segment -> conv2 partial for out rows t-2..t+2
//   (oring, init=b2).
//   out row g=s-4 completes -> *pdf, +x, store.
// ---------------------------------------------------------------------------
__global__ __launch_bounds__(256, 4) void fused_kernel(
    const float* __restrict__ x,
    const float* __restrict__ w1,  // (C,25)
    const float* __restrict__ b1,  // (C,)
    const float* __restrict__ w2,  // (C,25)
    const float* __restrict__ b2,  // (C,)
    const float* __restrict__ pdfm,
    float* __restrict__ out,
    int C) {
  const int tid = threadIdx.x;
  const int lane = tid & 31;
  const int group = tid >> 5;              // 0..7
  const int tile = blockIdx.x;             // 0..3
  const int c = blockIdx.y;                // channel (uniform per block)
  const int b = blockIdx.z * 8 + group;    // batch
  const int g0 = tile * TROWS;
  const int j0 = lane * 4;                 // output cols j0..j0+3

  const size_t plane = (size_t)(b * C + c) * (WDIM * HDIM);
  const float* xp = x + plane;
  float* op = out + plane;

  // Uniform (per-block) weights -> scalar registers.
  float w1s[25], w2s[25];
#pragma unroll
  for (int k = 0; k < 25; ++k) w1s[k] = w1[c * 25 + k];
#pragma unroll
  for (int k = 0; k < 25; ++k) w2s[k] = w2[c * 25 + k];
  const float b1v = b1[c];
  const float b2v = b2[c];

  // Rings (statically indexed after unroll -> registers).
  float vring[5][4];  // partial conv1 rows, own cols j0..j0+3 (init b1)
  float oring[5][4];  // partial conv2 rows, own cols j0..j0+3 (init b2)
#pragma unroll
  for (int r = 0; r < 5; ++r) {
#pragma unroll
    for (int q = 0; q < 4; ++q) { vring[r][q] = b1v; oring[r][q] = b2v; }
  }

  const bool lane_l = (lane >= 1) && (lane < 28);  // x cols j0-2..j0-1 exist
  const bool lane_b = (lane < 28);                 // x cols j0..j0+3 exist
  const bool lane_r = (lane <= 26);                // x cols j0+4..j0+5 exist
  const int s_base = g0 - 4;

  for (int chunk = 0; chunk < 8; ++chunk) {
#pragma unroll
    for (int u = 0; u < 5; ++u) {
      const int s = s_base + chunk * 5 + u;  // current x row
      // ---- 1. load x row s: 8 cols j0-2..j0+5, zero-padded ----
      const bool rv = (s >= 0) && (s < WDIM);
      const float* xrow = xp + s * HDIM;
      float2 lx = make_float2(0.f, 0.f);
      float4 bv = make_float4(0.f, 0.f, 0.f, 0.f);
      float2 rx = make_float2(0.f, 0.f);
      if (rv && lane_l) lx = *reinterpret_cast<const float2*>(xrow + j0 - 2);
      if (rv && lane_b) bv = *reinterpret_cast<const float4*>(xrow + j0);
      if (rv && lane_r) rx = *reinterpret_cast<const float2*>(xrow + j0 + 4);
      float xr[8];
      xr[0] = lx.x; xr[1] = lx.y;
      xr[2] = bv.x; xr[3] = bv.y; xr[4] = bv.z; xr[5] = bv.w;
      xr[6] = rx.x; xr[7] = rx.y;

      // ---- 2. recycle v slot for row t = s+2 (init = b1) ----
#pragma unroll
      for (int q = 0; q < 4; ++q) vring[(u + 2) % 5][q] = b1v;

      // ---- 3. conv1: x row s -> own 4 cols of v rows s-2..s+2 ----
#pragma unroll
      for (int k = 0; k < 5; ++k) {
        const int slot = (u + 3 + k) % 5;  // v row t = s-2+k
        const int dr = 4 - k;              // s = t-2+dr
#pragma unroll
        for (int dc = 0; dc < 5; ++dc) {
          const float w = w1s[dr * 5 + dc];
#pragma unroll
          for (int cc = 0; cc < 4; ++cc)
            vring[slot][cc] = fmaf(w, xr[cc + dc], vring[slot][cc]);
        }
      }

      // ---- 4. finalize v row t = s-2: relu (0 for pad rows / idle lanes) ----
      const int t = s - 2;
      const bool tv = (t >= 0) && (t < WDIM) && lane_b;
      float vcv[4];
#pragma unroll
      for (int q = 0; q < 4; ++q)
        vcv[q] = tv ? fmaxf(vring[(u + 3) % 5][q], 0.f) : 0.f;

      // ---- 4b. v-halo via cross-lane shuffle (width 32 segments) ----
      // left halo: lane-1's cols j0-2, j0-1 (its vcv[2], vcv[3])
      float lh0 = __shfl_up(vcv[2], 1, 32);
      float lh1 = __shfl_up(vcv[3], 1, 32);
      if (lane == 0) { lh0 = 0.f; lh1 = 0.f; }
      // right halo: lane+1's cols j0+4, j0+5 (its vcv[0], vcv[1]);
      // lane 27 reads lane 28 whose vcv==0 (padding) -- no mask needed.
      float rh0 = __shfl_down(vcv[0], 1, 32);
      float rh1 = __shfl_down(vcv[1], 1, 32);
      float vv[8];
      vv[0] = lh0; vv[1] = lh1;
      vv[2] = vcv[0]; vv[3] = vcv[1]; vv[4] = vcv[2]; vv[5] = vcv[3];
      vv[6] = rh0; vv[7] = rh1;

      // ---- 5. recycle out slot for row g = s (init = b2) ----
#pragma unroll
      for (int q = 0; q < 4; ++q) oring[u][q] = b2v;

      // ---- 6. conv2: v row t -> own 4 cols of out rows t-2..t+2 ----
#pragma unroll
      for (int k = 0; k < 5; ++k) {
        const int slot = (u + 1 + k) % 5;  // out row g = s-4+k
        const int dr = 4 - k;              // t = g-2+dr
#pragma unroll
        for (int dc = 0; dc < 5; ++dc) {
          const float w = w2s[dr * 5 + dc];
#pragma unroll
          for (int co = 0; co < 4; ++co)
            oring[slot][co] = fmaf(w, vv[co + dc], oring[slot][co]);
        }
      }

      // ---- 7. finalize out row g = s-4: *pdf, +x, store ----
      const int g = s - 4;
      if ((g >= g0) && (g < g0 + TROWS) && lane_b) {
        const float4 pv = *reinterpret_cast<const float4*>(pdfm + g * HDIM + j0);
        const float4 xcv = *reinterpret_cast<const float4*>(xp + g * HDIM + j0);
        float4 o;
        o.x = xcv.x + oring[(u + 1) % 5][0] * pv.x;
        o.y = xcv.y + oring[(u + 1) % 5][1] * pv.y;
        o.z = xcv.z + oring[(u + 1) % 5][2] * pv.z;
        o.w = xcv.w + oring[(u + 1) % 5][3] * pv.w;
        *reinterpret_cast<float4*>(op + g * HDIM + j0) = o;
      }
    }
  }
}

extern "C" void kernel_launch(void* const* d_in, const int* in_sizes, int n_in,
                              void* d_out, int out_size, void* d_ws, size_t ws_size,
                              hipStream_t stream) {
  const float* x    = (const float*)d_in[0];
  const float* w1   = (const float*)d_in[1];
  const float* b1   = (const float*)d_in[2];
  const float* w2   = (const float*)d_in[3];
  const float* b2   = (const float*)d_in[4];
  const float* loc  = (const float*)d_in[5];
  const float* scal = (const float*)d_in[6];
  const float* ps   = (const float*)d_in[7];
  float* out = (float*)d_out;
  float* pdfm = (float*)d_ws;  // 112*112 floats = 50 KB scratch

  const int C = in_sizes[2];                     // 256
  const int L = in_sizes[5] / 2;                 // 8

  hipLaunchKernelGGL(pdf_kernel, dim3((WDIM * HDIM + 255) / 256), dim3(256), 0,
                     stream, loc, scal, ps, pdfm, L);
  // grid: (4 row-tiles, channel, batch-octet); block = 8 batches x 32 lanes.
  dim3 grid(4, C, 2);
  hipLaunchKernelGGL(fused_kernel, grid, dim3(256), 0, stream, x, w1, b1, w2,
                     b2, pdfm, out, C);
}

// Round 4
// 144.793 us; speedup vs baseline: 1.8215x; 1.2227x over previous
//
#include <hip/hip_runtime.h>
#include <cmath>

// Problem constants (fixed by setup_inputs): B=16, C=256, W=H=112, L=8.
#define WDIM 112
#define HDIM 112
#define TROWS 28   // output rows per tile (4 tiles cover 112)

// ---------------------------------------------------------------------------
// Kernel 1: pdf_mean[i][j] (112x112, 50KB -> L2-resident)
// ---------------------------------------------------------------------------
__global__ __launch_bounds__(256) void pdf_kernel(
    const float* __restrict__ loc,   // (L,2)
    const float* __restrict__ scal,  // (L,2)
    const float* __restrict__ pscal, // (1,)
    float* __restrict__ pdfm,        // (112*112,)
    int L) {
  int idx = blockIdx.x * 256 + threadIdx.x;
  if (idx >= WDIM * HDIM) return;
  int i = idx / HDIM;
  int j = idx - i * HDIM;
  float ps = pscal[0];
  float px = (float)i * ps;
  float py = (float)j * ps;
  const float LOG2PI = 1.8378770664093453f;  // log(2*pi)
  float s = 0.f;
  for (int l = 0; l < L; ++l) {
    float lx = loc[2 * l + 0], ly = loc[2 * l + 1];
    float sx = scal[2 * l + 0], sy = scal[2 * l + 1];
    float dx = (px - lx) / sx;
    float dy = (py - ly) / sy;
    float logp = -0.5f * (dx * dx + dy * dy) - (logf(sx) + logf(sy)) - LOG2PI;
    s += expf(logp);
  }
  pdfm[idx] = s / (float)L;
}

// ---------------------------------------------------------------------------
// Kernel 2: register-streaming fused depthwise conv->relu->conv->*pdf->+x.
// No LDS, no barriers. Block = 256 threads = 8 groups of 32 lanes.
// Group: one (b,c) 28-row tile; lane owns 4 cols (lanes 28..31 idle/zero).
// Channel uniform per block -> weights live in SGPRs.
//
// 36 streaming steps (s in [g0-4, g0+31]), ring period 6, chunk-of-6 unroll
// so every ring index is a compile-time constant (rule: no runtime indexing).
// Per step s:
//   prefetch x row s+1 (own 4 cols, ONE masked float4) -> xring[(u+1)%6]
//   xr[8] = xring[u] widened +-2 via __shfl (x halo from neighbor lanes)
//   conv1: x row s -> own 4 cols of v rows s-2..s+2 (vring, init=b1)
//   v row t=s-2 done -> relu -> v halo via __shfl -> conv2 partials for out
//   rows t-2..t+2 (oring, init=b2)
//   out row g=s-4 done -> o*pdf + xring[(u+2)%6] (residual, no reload), store
// ---------------------------------------------------------------------------
__global__ __launch_bounds__(256, 4) void fused_kernel(
    const float* __restrict__ x,
    const float* __restrict__ w1,  // (C,25)
    const float* __restrict__ b1,  // (C,)
    const float* __restrict__ w2,  // (C,25)
    const float* __restrict__ b2,  // (C,)
    const float* __restrict__ pdfm,
    float* __restrict__ out,
    int C) {
  const int tid = threadIdx.x;
  const int lane = tid & 31;
  const int group = tid >> 5;              // 0..7
  const int tile = blockIdx.x;             // 0..3
  const int c = blockIdx.y;                // channel (uniform per block)
  const int b = blockIdx.z * 8 + group;    // batch
  const int g0 = tile * TROWS;
  const int j0 = lane * 4;                 // output cols j0..j0+3

  const size_t plane = (size_t)(b * C + c) * (WDIM * HDIM);
  const float* xp = x + plane;
  float* op = out + plane;

  // Uniform (per-block) weights -> scalar registers.
  float w1s[25], w2s[25];
#pragma unroll
  for (int k = 0; k < 25; ++k) w1s[k] = w1[c * 25 + k];
#pragma unroll
  for (int k = 0; k < 25; ++k) w2s[k] = w2[c * 25 + k];
  const float b1v = b1[c];
  const float b2v = b2[c];

  // Rings (statically indexed after unroll -> registers).
  float xring[6][4];  // x rows (own 4 cols): prefetch + residual reuse
  float vring[6][4];  // partial conv1 rows (init b1)
  float oring[6][4];  // partial conv2 rows (init b2)
#pragma unroll
  for (int r = 0; r < 6; ++r) {
#pragma unroll
    for (int q = 0; q < 4; ++q) {
      xring[r][q] = 0.f; vring[r][q] = b1v; oring[r][q] = b2v;
    }
  }

  const bool lane_b = (lane < 28);
  const int s_base = g0 - 4;
  const int s_last = g0 + 31;

  // Prologue: load x row s_base into xring[0].
  {
    float4 t = make_float4(0.f, 0.f, 0.f, 0.f);
    if (s_base >= 0 && lane_b)
      t = *reinterpret_cast<const float4*>(xp + s_base * HDIM + j0);
    xring[0][0] = t.x; xring[0][1] = t.y; xring[0][2] = t.z; xring[0][3] = t.w;
  }

  for (int chunk = 0; chunk < 6; ++chunk) {
#pragma unroll
    for (int u = 0; u < 6; ++u) {
      const int s = s_base + chunk * 6 + u;  // current x row

      // ---- 1. prefetch x row s+1 -> xring[(u+1)%6] ----
      {
        const int sp = s + 1;
        float4 t = make_float4(0.f, 0.f, 0.f, 0.f);
        if (sp >= 0 && sp < WDIM && sp <= s_last && lane_b)
          t = *reinterpret_cast<const float4*>(xp + sp * HDIM + j0);
        xring[(u + 1) % 6][0] = t.x; xring[(u + 1) % 6][1] = t.y;
        xring[(u + 1) % 6][2] = t.z; xring[(u + 1) % 6][3] = t.w;
      }

      // ---- 2. assemble xr[8] = cols j0-2..j0+5 via cross-lane shuffle ----
      const float ox0 = xring[u][0], ox1 = xring[u][1];
      const float ox2 = xring[u][2], ox3 = xring[u][3];
      float xl0 = __shfl_up(ox2, 1, 32);
      float xl1 = __shfl_up(ox3, 1, 32);
      if (lane == 0) { xl0 = 0.f; xl1 = 0.f; }
      const float xh0 = __shfl_down(ox0, 1, 32);  // lane28 holds 0 -> pad ok
      const float xh1 = __shfl_down(ox1, 1, 32);
      float xr[8];
      xr[0] = xl0; xr[1] = xl1;
      xr[2] = ox0; xr[3] = ox1; xr[4] = ox2; xr[5] = ox3;
      xr[6] = xh0; xr[7] = xh1;

      // ---- 3. open v slot for row s+2 (init = b1) ----
#pragma unroll
      for (int q = 0; q < 4; ++q) vring[(u + 2) % 6][q] = b1v;

      // ---- 4. conv1: x row s -> own 4 cols of v rows s-2..s+2 ----
#pragma unroll
      for (int k = 0; k < 5; ++k) {
        const int slot = (u + 4 + k) % 6;  // v row t = s-2+k
        const int dr = 4 - k;              // s = t-2+dr
#pragma unroll
        for (int dc = 0; dc < 5; ++dc) {
          const float w = w1s[dr * 5 + dc];
#pragma unroll
          for (int cc = 0; cc < 4; ++cc)
            vring[slot][cc] = fmaf(w, xr[cc + dc], vring[slot][cc]);
        }
      }

      // ---- 5. finalize v row t = s-2: relu (0 for pad rows / idle lanes) ----
      const int t_ = s - 2;
      const bool tval = (t_ >= 0) && (t_ < WDIM);
      float vc0 = (tval && lane_b) ? fmaxf(vring[(u + 4) % 6][0], 0.f) : 0.f;
      float vc1 = (tval && lane_b) ? fmaxf(vring[(u + 4) % 6][1], 0.f) : 0.f;
      float vc2 = (tval && lane_b) ? fmaxf(vring[(u + 4) % 6][2], 0.f) : 0.f;
      float vc3 = (tval && lane_b) ? fmaxf(vring[(u + 4) % 6][3], 0.f) : 0.f;

      // ---- 5b. v halo via cross-lane shuffle ----
      float vl0 = __shfl_up(vc2, 1, 32);
      float vl1 = __shfl_up(vc3, 1, 32);
      if (lane == 0) { vl0 = 0.f; vl1 = 0.f; }
      const float vh0 = __shfl_down(vc0, 1, 32);  // lane28 vc==0 -> pad ok
      const float vh1 = __shfl_down(vc1, 1, 32);
      float vv[8];
      vv[0] = vl0; vv[1] = vl1;
      vv[2] = vc0; vv[3] = vc1; vv[4] = vc2; vv[5] = vc3;
      vv[6] = vh0; vv[7] = vh1;

      // ---- 6. open o slot for row s (init = b2) ----
#pragma unroll
      for (int q = 0; q < 4; ++q) oring[u][q] = b2v;

      // ---- 7. conv2: v row t -> own 4 cols of out rows t-2..t+2 ----
#pragma unroll
      for (int k = 0; k < 5; ++k) {
        const int slot = (u + 2 + k) % 6;  // out row g = s-4+k
        const int dr = 4 - k;              // t = g-2+dr
#pragma unroll
        for (int dc = 0; dc < 5; ++dc) {
          const float w = w2s[dr * 5 + dc];
#pragma unroll
          for (int co = 0; co < 4; ++co)
            oring[slot][co] = fmaf(w, vv[co + dc], oring[slot][co]);
        }
      }

      // ---- 8. finalize out row g = s-4: *pdf + residual (from xring) ----
      const int g = s - 4;
      if ((g >= g0) && (g < g0 + TROWS) && lane_b) {
        const float4 pv = *reinterpret_cast<const float4*>(pdfm + g * HDIM + j0);
        float4 o;
        o.x = fmaf(oring[(u + 2) % 6][0], pv.x, xring[(u + 2) % 6][0]);
        o.y = fmaf(oring[(u + 2) % 6][1], pv.y, xring[(u + 2) % 6][1]);
        o.z = fmaf(oring[(u + 2) % 6][2], pv.z, xring[(u + 2) % 6][2]);
        o.w = fmaf(oring[(u + 2) % 6][3], pv.w, xring[(u + 2) % 6][3]);
        *reinterpret_cast<float4*>(op + g * HDIM + j0) = o;
      }
    }
  }
}

extern "C" void kernel_launch(void* const* d_in, const int* in_sizes, int n_in,
                              void* d_out, int out_size, void* d_ws, size_t ws_size,
                              hipStream_t stream) {
  const float* x    = (const float*)d_in[0];
  const float* w1   = (const float*)d_in[1];
  const float* b1   = (const float*)d_in[2];
  const float* w2   = (const float*)d_in[3];
  const float* b2   = (const float*)d_in[4];
  const float* loc  = (const float*)d_in[5];
  const float* scal = (const float*)d_in[6];
  const float* ps   = (const float*)d_in[7];
  float* out = (float*)d_out;
  float* pdfm = (float*)d_ws;  // 112*112 floats = 50 KB scratch

  const int C = in_sizes[2];                     // 256
  const int L = in_sizes[5] / 2;                 // 8

  hipLaunchKernelGGL(pdf_kernel, dim3((WDIM * HDIM + 255) / 256), dim3(256), 0,
                     stream, loc, scal, ps, pdfm, L);
  // grid: (4 row-tiles, channel, batch-octet); block = 8 batches x 32 lanes.
  dim3 grid(4, C, 2);
  hipLaunchKernelGGL(fused_kernel, grid, dim3(256), 0, stream, x, w1, b1, w2,
                     b2, pdfm, out, C);
}

// Round 5
// 144.004 us; speedup vs baseline: 1.8315x; 1.0055x over previous
//
#include <hip/hip_runtime.h>
#include <cmath>

// Problem constants (fixed by setup_inputs): B=16, C=256, W=H=112, L=8.
#define WDIM 112
#define HDIM 112
#define TROWS 28   // output rows per tile (4 tiles cover 112)

typedef _Float16 half2_t __attribute__((ext_vector_type(2)));

// v_dot2_f32_f16: c += a.x*b.x + a.y*b.y (f16 inputs, f32 accumulate)
__device__ __forceinline__ float dot2(unsigned int a, unsigned int b, float c) {
  return __builtin_amdgcn_fdot2(__builtin_bit_cast(half2_t, a),
                                __builtin_bit_cast(half2_t, b), c, false);
}
// pack 2 f32 -> packed f16 pair (RTZ)
__device__ __forceinline__ unsigned int pkh(float lo, float hi) {
  return __builtin_bit_cast(unsigned int, __builtin_amdgcn_cvt_pkrtz(lo, hi));
}
// (hi16 of b, lo16 of a) -> pair (b.hi, a.lo): ({a,b} >> 16) low 32 bits
__device__ __forceinline__ unsigned int algn(unsigned int a, unsigned int b) {
  return __builtin_amdgcn_alignbit(a, b, 16);
}

// ---------------------------------------------------------------------------
// Kernel 1: pdf_mean[i][j] (112x112, 50KB -> L2-resident)
// ---------------------------------------------------------------------------
__global__ __launch_bounds__(256) void pdf_kernel(
    const float* __restrict__ loc,   // (L,2)
    const float* __restrict__ scal,  // (L,2)
    const float* __restrict__ pscal, // (1,)
    float* __restrict__ pdfm,        // (112*112,)
    int L) {
  int idx = blockIdx.x * 256 + threadIdx.x;
  if (idx >= WDIM * HDIM) return;
  int i = idx / HDIM;
  int j = idx - i * HDIM;
  float ps = pscal[0];
  float px = (float)i * ps;
  float py = (float)j * ps;
  const float LOG2PI = 1.8378770664093453f;  // log(2*pi)
  float s = 0.f;
  for (int l = 0; l < L; ++l) {
    float lx = loc[2 * l + 0], ly = loc[2 * l + 1];
    float sx = scal[2 * l + 0], sy = scal[2 * l + 1];
    float dx = (px - lx) / sx;
    float dy = (py - ly) / sy;
    float logp = -0.5f * (dx * dx + dy * dy) - (logf(sx) + logf(sy)) - LOG2PI;
    s += expf(logp);
  }
  pdfm[idx] = s / (float)L;
}

// ---------------------------------------------------------------------------
// Kernel 2: register-streaming fused conv->relu->conv->*pdf->+x, f16 dot2.
// No LDS, no barriers. Block = 256 threads = 8 groups of 32 lanes.
// Group: one (b,c) 28-row tile; lane owns 4 cols (lanes 28..31 idle/zero).
// Channel uniform per block -> packed f16 weight pairs in SGPRs.
//
// 36 steps (s in [g0-4, g0+31]), rings period 6, chunk-of-6 unroll (all ring
// indices compile-time). Per step s:
//   prefetch x row s+1 (1 masked float4) -> packed f16 pairs + halo shuffles
//   issued NOW (latency covered by this step's 120 dot2s), consumed next step
//   conv1: row s -> own 4 cols of v rows s-2..s+2; 3 dot2/col/row
//          (pairs at offsets -2,0,+2 via alignbit; bias folded into k=4 acc)
//   relu row t=s-2 -> pack -> v-halo shuffles -> conv2 into out rows t-2..t+2
//   out row g=s-4 done -> *pdf + x (reloaded, cache-hot), store
// ---------------------------------------------------------------------------
__global__ __launch_bounds__(256, 4) void fused_kernel(
    const float* __restrict__ x,
    const float* __restrict__ w1,  // (C,25)
    const float* __restrict__ b1,  // (C,)
    const float* __restrict__ w2,  // (C,25)
    const float* __restrict__ b2,  // (C,)
    const float* __restrict__ pdfm,
    float* __restrict__ out,
    int C) {
  const int tid = threadIdx.x;
  const int lane = tid & 31;
  const int group = tid >> 5;              // 0..7
  const int tile = blockIdx.x;             // 0..3
  const int c = blockIdx.y;                // channel (uniform per block)
  const int b = blockIdx.z * 8 + group;    // batch
  const int g0 = tile * TROWS;
  const int j0 = lane * 4;                 // output cols j0..j0+3

  const size_t plane = (size_t)(b * C + c) * (WDIM * HDIM);
  const float* xp = x + plane;
  float* op = out + plane;

  // Packed f16 weight pairs -> SGPRs via readfirstlane (uniform per block).
  // wpa[r]=(w[r,0],w[r,1]) wpb[r]=(w[r,2],w[r,3]) wpc[r]=(w[r,4],0)
  unsigned int w1pa[5], w1pb[5], w1pc[5], w2pa[5], w2pb[5], w2pc[5];
#pragma unroll
  for (int r = 0; r < 5; ++r) {
    const float* wr = w1 + c * 25 + r * 5;
    w1pa[r] = __builtin_amdgcn_readfirstlane(pkh(wr[0], wr[1]));
    w1pb[r] = __builtin_amdgcn_readfirstlane(pkh(wr[2], wr[3]));
    w1pc[r] = __builtin_amdgcn_readfirstlane(pkh(wr[4], 0.f));
  }
#pragma unroll
  for (int r = 0; r < 5; ++r) {
    const float* wr = w2 + c * 25 + r * 5;
    w2pa[r] = __builtin_amdgcn_readfirstlane(pkh(wr[0], wr[1]));
    w2pb[r] = __builtin_amdgcn_readfirstlane(pkh(wr[2], wr[3]));
    w2pc[r] = __builtin_amdgcn_readfirstlane(pkh(wr[4], 0.f));
  }
  const float b1v = b1[c];
  const float b2v = b2[c];

  // f32 accumulator rings (statically indexed after unroll -> registers).
  float vring[6][4];  // partial conv1 rows
  float oring[6][4];  // partial conv2 rows
#pragma unroll
  for (int r = 0; r < 6; ++r) {
#pragma unroll
    for (int q = 0; q < 4; ++q) { vring[r][q] = 0.f; oring[r][q] = 0.f; }
  }

  const bool lane_b = (lane < 28);
  const int s_base = g0 - 4;

  // Prologue: row s_base packed pairs + halo shuffles.
  unsigned int cur01, cur23, curA, curD;
  {
    float4 t = make_float4(0.f, 0.f, 0.f, 0.f);
    if (s_base >= 0 && lane_b)
      t = *reinterpret_cast<const float4*>(xp + s_base * HDIM + j0);
    cur01 = pkh(t.x, t.y);
    cur23 = pkh(t.z, t.w);
    curA = __shfl_up(cur23, 1, 32);
    if (lane == 0) curA = 0u;
    curD = __shfl_down(cur01, 1, 32);
  }

  for (int chunk = 0; chunk < 6; ++chunk) {
#pragma unroll
    for (int u = 0; u < 6; ++u) {
      const int s = s_base + chunk * 6 + u;  // current x row

      // ---- 1. prefetch x row s+1; pack + halo shuffles issued early ----
      unsigned int nxt01, nxt23, nxtA, nxtD;
      {
        const int sp = s + 1;
        float4 t = make_float4(0.f, 0.f, 0.f, 0.f);
        if (sp >= 0 && sp < WDIM && lane_b)
          t = *reinterpret_cast<const float4*>(xp + sp * HDIM + j0);
        nxt01 = pkh(t.x, t.y);
        nxt23 = pkh(t.z, t.w);
        nxtA = __shfl_up(nxt23, 1, 32);
        if (lane == 0) nxtA = 0u;
        nxtD = __shfl_down(nxt01, 1, 32);  // lane27 <- lane28 == 0 (pad ok)
      }

      // ---- 2. odd-offset pairs for row s (cheap VALU, from cached halos) ----
      const unsigned int o1 = algn(cur01, curA);   // (x[j0-1], x[j0])
      const unsigned int o2 = algn(cur23, cur01);  // (x[j0+1], x[j0+2])
      const unsigned int o3 = algn(curD, cur23);   // (x[j0+3], x[j0+4])
      const unsigned int o4 = curD >> 16;          // (x[j0+5], 0)
      // per-col tap pairs: taps c-2..c+2 = pA + pB + pC(w4,0)
      const unsigned int p1[4] = {curA, o1, cur01, o2};
      const unsigned int p2[4] = {cur01, o2, cur23, o3};
      const unsigned int p3[4] = {cur23, o3, curD, o4};

      // ---- 3. conv1: row s -> v rows s-2..s+2 (k=4 opens slot, bias fold) ----
#pragma unroll
      for (int k = 4; k >= 0; --k) {
        const int slot = (u + 4 + k) % 6;  // v row t = s-2+k
        const int dr = 4 - k;              // weight row: s = t-2+dr
#pragma unroll
        for (int cc = 0; cc < 4; ++cc) {
          float acc = (k == 4) ? b1v : vring[slot][cc];
          acc = dot2(w1pa[dr], p1[cc], acc);
          acc = dot2(w1pb[dr], p2[cc], acc);
          vring[slot][cc] = dot2(w1pc[dr], p3[cc], acc);
        }
      }

      // ---- 4. finalize v row t=s-2: relu (0 for pad rows / idle lanes) ----
      const int t_ = s - 2;
      const bool tval = (t_ >= 0) && (t_ < WDIM);
      const int fs = (u + 4) % 6;
      const float vc0 = (tval && lane_b) ? fmaxf(vring[fs][0], 0.f) : 0.f;
      const float vc1 = (tval && lane_b) ? fmaxf(vring[fs][1], 0.f) : 0.f;
      const float vc2 = (tval && lane_b) ? fmaxf(vring[fs][2], 0.f) : 0.f;
      const float vc3 = (tval && lane_b) ? fmaxf(vring[fs][3], 0.f) : 0.f;

      // ---- 5. pack v + halo shuffles + odd pairs ----
      const unsigned int V01 = pkh(vc0, vc1);
      const unsigned int V23 = pkh(vc2, vc3);
      unsigned int vA = __shfl_up(V23, 1, 32);
      if (lane == 0) vA = 0u;
      const unsigned int vD = __shfl_down(V01, 1, 32);  // lane28 vc==0 pad ok
      const unsigned int q1 = algn(V01, vA);
      const unsigned int q2 = algn(V23, V01);
      const unsigned int q3 = algn(vD, V23);
      const unsigned int q4 = vD >> 16;
      const unsigned int r1[4] = {vA, q1, V01, q2};
      const unsigned int r2[4] = {V01, q2, V23, q3};
      const unsigned int r3[4] = {V23, q3, vD, q4};

      // ---- 6. conv2: v row t -> out rows t-2..t+2 (k=4 opens, bias fold) ----
#pragma unroll
      for (int k = 4; k >= 0; --k) {
        const int slot = (u + 2 + k) % 6;  // out row g = s-4+k
        const int dr = 4 - k;              // weight row: t = g-2+dr
#pragma unroll
        for (int cc = 0; cc < 4; ++cc) {
          float acc = (k == 4) ? b2v : oring[slot][cc];
          acc = dot2(w2pa[dr], r1[cc], acc);
          acc = dot2(w2pb[dr], r2[cc], acc);
          oring[slot][cc] = dot2(w2pc[dr], r3[cc], acc);
        }
      }

      // ---- 7. finalize out row g=s-4: *pdf + x (cache-hot reload), store ----
      const int g = s - 4;
      if (g >= g0 && lane_b) {  // g < g0+TROWS always (max g = g0+27)
        const int os = (u + 2) % 6;
        const float4 pv = *reinterpret_cast<const float4*>(pdfm + g * HDIM + j0);
        const float4 xr = *reinterpret_cast<const float4*>(xp + g * HDIM + j0);
        float4 o;
        o.x = fmaf(oring[os][0], pv.x, xr.x);
        o.y = fmaf(oring[os][1], pv.y, xr.y);
        o.z = fmaf(oring[os][2], pv.z, xr.z);
        o.w = fmaf(oring[os][3], pv.w, xr.w);
        *reinterpret_cast<float4*>(op + g * HDIM + j0) = o;
      }

      // ---- 8. rotate prefetched row into place (SSA, no movs) ----
      cur01 = nxt01; cur23 = nxt23; curA = nxtA; curD = nxtD;
    }
  }
}

extern "C" void kernel_launch(void* const* d_in, const int* in_sizes, int n_in,
                              void* d_out, int out_size, void* d_ws, size_t ws_size,
                              hipStream_t stream) {
  const float* x    = (const float*)d_in[0];
  const float* w1   = (const float*)d_in[1];
  const float* b1   = (const float*)d_in[2];
  const float* w2   = (const float*)d_in[3];
  const float* b2   = (const float*)d_in[4];
  const float* loc  = (const float*)d_in[5];
  const float* scal = (const float*)d_in[6];
  const float* ps   = (const float*)d_in[7];
  float* out = (float*)d_out;
  float* pdfm = (float*)d_ws;  // 112*112 floats = 50 KB scratch

  const int C = in_sizes[2];                     // 256
  const int L = in_sizes[5] / 2;                 // 8

  hipLaunchKernelGGL(pdf_kernel, dim3((WDIM * HDIM + 255) / 256), dim3(256), 0,
                     stream, loc, scal, ps, pdfm, L);
  // grid: (4 row-tiles, channel, batch-octet); block = 8 batches x 32 lanes.
  dim3 grid(4, C, 2);
  hipLaunchKernelGGL(fused_kernel, grid, dim3(256), 0, stream, x, w1, b1, w2,
                     b2, pdfm, out, C);
}

// Round 6
// 128.582 us; speedup vs baseline: 2.0511x; 1.1199x over previous
//
#include <hip/hip_runtime.h>
#include <cmath>

// Problem constants (fixed by setup_inputs): B=16, C=256, W=H=112, L=8.
#define WDIM 112
#define HDIM 112
#define TROWS 28   // output rows per tile (4 tiles cover 112)

typedef _Float16 half2_t __attribute__((ext_vector_type(2)));

// v_dot2_f32_f16: c += a.x*b.x + a.y*b.y (f16 inputs, f32 accumulate)
__device__ __forceinline__ float dot2(unsigned int a, unsigned int b, float c) {
  return __builtin_amdgcn_fdot2(__builtin_bit_cast(half2_t, a),
                                __builtin_bit_cast(half2_t, b), c, false);
}
// pack 2 f32 -> packed f16 pair (RTZ)
__device__ __forceinline__ unsigned int pkh(float lo, float hi) {
  return __builtin_bit_cast(unsigned int, __builtin_amdgcn_cvt_pkrtz(lo, hi));
}
// ({b,a} >> 16) low 32 = (a.hi, b.lo) -> pair straddling two packed pairs
__device__ __forceinline__ unsigned int algn(unsigned int a, unsigned int b) {
  return __builtin_amdgcn_alignbit(a, b, 16);
}
__device__ __forceinline__ float lo16f(unsigned int p) {
  return (float)__builtin_bit_cast(half2_t, p)[0];
}
__device__ __forceinline__ float hi16f(unsigned int p) {
  return (float)__builtin_bit_cast(half2_t, p)[1];
}

// ---------------------------------------------------------------------------
// Kernel 1: pdf_mean[i][j] (112x112, 50KB -> L2-resident)
// ---------------------------------------------------------------------------
__global__ __launch_bounds__(256) void pdf_kernel(
    const float* __restrict__ loc,   // (L,2)
    const float* __restrict__ scal,  // (L,2)
    const float* __restrict__ pscal, // (1,)
    float* __restrict__ pdfm,        // (112*112,)
    int L) {
  int idx = blockIdx.x * 256 + threadIdx.x;
  if (idx >= WDIM * HDIM) return;
  int i = idx / HDIM;
  int j = idx - i * HDIM;
  float ps = pscal[0];
  float px = (float)i * ps;
  float py = (float)j * ps;
  const float LOG2PI = 1.8378770664093453f;  // log(2*pi)
  float s = 0.f;
  for (int l = 0; l < L; ++l) {
    float lx = loc[2 * l + 0], ly = loc[2 * l + 1];
    float sx = scal[2 * l + 0], sy = scal[2 * l + 1];
    float dx = (px - lx) / sx;
    float dy = (py - ly) / sy;
    float logp = -0.5f * (dx * dx + dy * dy) - (logf(sx) + logf(sy)) - LOG2PI;
    s += expf(logp);
  }
  pdfm[idx] = s / (float)L;
}

// ---------------------------------------------------------------------------
// Kernel 2: register-streaming fused conv->relu->conv->*pdf->+x, f16 dot2,
// software-pipelined loads. No LDS, no barriers. 8 groups of 32 lanes/block.
// Group: one (b,c) 28-row tile; lane owns 4 cols (lanes 28..31 idle/zero).
//
// 36 steps (n=0..35, s=s_base+n), rings period 6, chunk-of-6 unroll.
// Pipeline per step n (row s):
//   A issue load x row s+2 -> fbuf[u&1]      (consumed 1.5 steps later)
//   B issue load pdf row g=s-4               (consumed at F, same step)
//   C pairs for row s from px ring + curA/curD (prepared at step n-1's G)
//   D conv1: row s -> v rows s-2..s+2 (vring; k=4 opens slot, bias folded)
//   E relu v row t=s-2 -> pack -> v-halo shuffles -> conv2 -> out rows t-2..t+2
//   F out row g: oring*pdf + unpack-f16(px ring residual), store
//   G pack fbuf[(u+1)&1] (row s+1) -> px ring slot (u+1)%6; halo shuffles
//     -> curA/curD. Load->pack distance = full step (~600cyc) + intra-step.
// ---------------------------------------------------------------------------
__global__ __launch_bounds__(256, 4) void fused_kernel(
    const float* __restrict__ x,
    const float* __restrict__ w1,  // (C,25)
    const float* __restrict__ b1,  // (C,)
    const float* __restrict__ w2,  // (C,25)
    const float* __restrict__ b2,  // (C,)
    const float* __restrict__ pdfm,
    float* __restrict__ out,
    int C) {
  const int tid = threadIdx.x;
  const int lane = tid & 31;
  const int group = tid >> 5;              // 0..7
  const int tile = blockIdx.x;             // 0..3
  const int c = blockIdx.y;                // channel (uniform per block)
  const int b = blockIdx.z * 8 + group;    // batch
  const int g0 = tile * TROWS;
  const int j0 = lane * 4;                 // output cols j0..j0+3

  const size_t plane = (size_t)(b * C + c) * (WDIM * HDIM);
  const float* xp = x + plane;
  float* op = out + plane;

  // Packed f16 weight pairs -> SGPRs via readfirstlane (uniform per block).
  unsigned int w1pa[5], w1pb[5], w1pc[5], w2pa[5], w2pb[5], w2pc[5];
#pragma unroll
  for (int r = 0; r < 5; ++r) {
    const float* wr = w1 + c * 25 + r * 5;
    w1pa[r] = __builtin_amdgcn_readfirstlane(pkh(wr[0], wr[1]));
    w1pb[r] = __builtin_amdgcn_readfirstlane(pkh(wr[2], wr[3]));
    w1pc[r] = __builtin_amdgcn_readfirstlane(pkh(wr[4], 0.f));
  }
#pragma unroll
  for (int r = 0; r < 5; ++r) {
    const float* wr = w2 + c * 25 + r * 5;
    w2pa[r] = __builtin_amdgcn_readfirstlane(pkh(wr[0], wr[1]));
    w2pb[r] = __builtin_amdgcn_readfirstlane(pkh(wr[2], wr[3]));
    w2pc[r] = __builtin_amdgcn_readfirstlane(pkh(wr[4], 0.f));
  }
  const float b1v = b1[c];
  const float b2v = b2[c];

  // Rings (statically indexed after unroll -> registers).
  unsigned int px01[6], px23[6];  // packed f16 x rows (also residual source)
  float vring[6][4];              // partial conv1 rows
  float oring[6][4];              // partial conv2 rows
#pragma unroll
  for (int r = 0; r < 6; ++r) {
    px01[r] = 0u; px23[r] = 0u;
#pragma unroll
    for (int q = 0; q < 4; ++q) { vring[r][q] = 0.f; oring[r][q] = 0.f; }
  }

  const bool lane_b = (lane < 28);
  const int s_base = g0 - 4;

  // Prologue: pack row s_base into px slot 0 + halo; raw row s_base+1 -> fbuf[1].
  unsigned int curA, curD;
  float4 fbuf0 = make_float4(0.f, 0.f, 0.f, 0.f);
  float4 fbuf1 = make_float4(0.f, 0.f, 0.f, 0.f);
  {
    float4 t = make_float4(0.f, 0.f, 0.f, 0.f);
    if (s_base >= 0 && lane_b)
      t = *reinterpret_cast<const float4*>(xp + s_base * HDIM + j0);
    const unsigned int c01 = pkh(t.x, t.y);
    const unsigned int c23 = pkh(t.z, t.w);
    px01[0] = c01; px23[0] = c23;
    curA = __shfl_up(c23, 1, 32);
    if (lane == 0) curA = 0u;
    curD = __shfl_down(c01, 1, 32);
    const int s1 = s_base + 1;
    if (s1 >= 0 && lane_b)  // s1 < WDIM always
      fbuf1 = *reinterpret_cast<const float4*>(xp + s1 * HDIM + j0);
  }

  for (int chunk = 0; chunk < 6; ++chunk) {
#pragma unroll
    for (int u = 0; u < 6; ++u) {
      const int s = s_base + chunk * 6 + u;  // current x row
      const int g = s - 4;                   // output row this step

      // ---- A. issue x load row s+2 -> fbuf[u&1] (no consumption here) ----
      {
        const int sp = s + 2;
        float4 t = make_float4(0.f, 0.f, 0.f, 0.f);
        if (sp >= 0 && sp < WDIM && lane_b)
          t = *reinterpret_cast<const float4*>(xp + sp * HDIM + j0);
        if ((u & 1) == 0) fbuf0 = t; else fbuf1 = t;
      }

      // ---- B. issue pdf load for row g (consumed at F) ----
      float4 pv = make_float4(0.f, 0.f, 0.f, 0.f);
      if (g >= g0 && lane_b)  // g < g0+TROWS always
        pv = *reinterpret_cast<const float4*>(pdfm + g * HDIM + j0);

      // ---- C. tap pairs for row s (from regs prepared at step n-1) ----
      const unsigned int a01 = px01[u], a23 = px23[u];
      const unsigned int o1 = algn(a01, curA);   // (x[j0-1], x[j0])
      const unsigned int o2 = algn(a23, a01);    // (x[j0+1], x[j0+2])
      const unsigned int o3 = algn(curD, a23);   // (x[j0+3], x[j0+4])
      const unsigned int o4 = curD >> 16;        // (x[j0+5], 0)
      const unsigned int p1[4] = {curA, o1, a01, o2};
      const unsigned int p2[4] = {a01, o2, a23, o3};
      const unsigned int p3[4] = {a23, o3, curD, o4};

      // ---- D. conv1: row s -> v rows s-2..s+2 (k=4 opens slot, bias fold) ----
#pragma unroll
      for (int k = 4; k >= 0; --k) {
        const int slot = (u + 4 + k) % 6;  // v row t = s-2+k
        const int dr = 4 - k;              // weight row: s = t-2+dr
#pragma unroll
        for (int cc = 0; cc < 4; ++cc) {
          float acc = (k == 4) ? b1v : vring[slot][cc];
          acc = dot2(w1pa[dr], p1[cc], acc);
          acc = dot2(w1pb[dr], p2[cc], acc);
          vring[slot][cc] = dot2(w1pc[dr], p3[cc], acc);
        }
      }

      // ---- E. finalize v row t=s-2: relu, pack, halo, conv2 ----
      const int t_ = s - 2;
      const bool tval = (t_ >= 0) && (t_ < WDIM);
      const int fs = (u + 4) % 6;
      const float vc0 = (tval && lane_b) ? fmaxf(vring[fs][0], 0.f) : 0.f;
      const float vc1 = (tval && lane_b) ? fmaxf(vring[fs][1], 0.f) : 0.f;
      const float vc2 = (tval && lane_b) ? fmaxf(vring[fs][2], 0.f) : 0.f;
      const float vc3 = (tval && lane_b) ? fmaxf(vring[fs][3], 0.f) : 0.f;
      const unsigned int V01 = pkh(vc0, vc1);
      const unsigned int V23 = pkh(vc2, vc3);
      unsigned int vA = __shfl_up(V23, 1, 32);
      if (lane == 0) vA = 0u;
      const unsigned int vD = __shfl_down(V01, 1, 32);  // lane28 vc==0 pad ok
      const unsigned int q1 = algn(V01, vA);
      const unsigned int q2 = algn(V23, V01);
      const unsigned int q3 = algn(vD, V23);
      const unsigned int q4 = vD >> 16;
      const unsigned int r1[4] = {vA, q1, V01, q2};
      const unsigned int r2[4] = {V01, q2, V23, q3};
      const unsigned int r3[4] = {V23, q3, vD, q4};
#pragma unroll
      for (int k = 4; k >= 0; --k) {
        const int slot = (u + 2 + k) % 6;  // out row gk = s-4+k
        const int dr = 4 - k;              // weight row: t = gk-2+dr
#pragma unroll
        for (int cc = 0; cc < 4; ++cc) {
          float acc = (k == 4) ? b2v : oring[slot][cc];
          acc = dot2(w2pa[dr], r1[cc], acc);
          acc = dot2(w2pb[dr], r2[cc], acc);
          oring[slot][cc] = dot2(w2pc[dr], r3[cc], acc);
        }
      }

      // ---- F. out row g: *pdf + residual (unpacked f16 from px ring) ----
      if (g >= g0 && lane_b) {
        const int os = (u + 2) % 6;
        const unsigned int rx01 = px01[os], rx23 = px23[os];
        float4 o;
        o.x = fmaf(oring[os][0], pv.x, lo16f(rx01));
        o.y = fmaf(oring[os][1], pv.y, hi16f(rx01));
        o.z = fmaf(oring[os][2], pv.z, lo16f(rx23));
        o.w = fmaf(oring[os][3], pv.w, hi16f(rx23));
        *reinterpret_cast<float4*>(op + g * HDIM + j0) = o;
      }

      // ---- G. pack row s+1 (loaded at step n-1) -> px slot (u+1)%6 ----
      {
        const float4 f = ((u & 1) == 0) ? fbuf1 : fbuf0;  // parity: row s+1
        const unsigned int n01 = pkh(f.x, f.y);
        const unsigned int n23 = pkh(f.z, f.w);
        px01[(u + 1) % 6] = n01;
        px23[(u + 1) % 6] = n23;
        unsigned int nA = __shfl_up(n23, 1, 32);
        if (lane == 0) nA = 0u;
        curA = nA;
        curD = __shfl_down(n01, 1, 32);
      }
    }
  }
}

extern "C" void kernel_launch(void* const* d_in, const int* in_sizes, int n_in,
                              void* d_out, int out_size, void* d_ws, size_t ws_size,
                              hipStream_t stream) {
  const float* x    = (const float*)d_in[0];
  const float* w1   = (const float*)d_in[1];
  const float* b1   = (const float*)d_in[2];
  const float* w2   = (const float*)d_in[3];
  const float* b2   = (const float*)d_in[4];
  const float* loc  = (const float*)d_in[5];
  const float* scal = (const float*)d_in[6];
  const float* ps   = (const float*)d_in[7];
  float* out = (float*)d_out;
  float* pdfm = (float*)d_ws;  // 112*112 floats = 50 KB scratch

  const int C = in_sizes[2];                     // 256
  const int L = in_sizes[5] / 2;                 // 8

  hipLaunchKernelGGL(pdf_kernel, dim3((WDIM * HDIM + 255) / 256), dim3(256), 0,
                     stream, loc, scal, ps, pdfm, L);
  // grid: (4 row-tiles, channel, batch-octet); block = 8 batches x 32 lanes.
  dim3 grid(4, C, 2);
  hipLaunchKernelGGL(fused_kernel, grid, dim3(256), 0, stream, x, w1, b1, w2,
                     b2, pdfm, out, C);
}

// Round 8
// 102.876 us; speedup vs baseline: 2.5637x; 1.2499x over previous
//
#include <hip/hip_runtime.h>
#include <cmath>

// Problem constants (fixed by setup_inputs): B=16, C=256, W=H=112, L=8.
#define WDIM 112
#define HDIM 112
#define TROWS 28   // output rows per tile (4 tiles cover 112)

typedef _Float16 half2_t __attribute__((ext_vector_type(2)));
typedef float fvec4 __attribute__((ext_vector_type(4)));  // native vec for nt-store

// v_dot2_f32_f16: c += a.x*b.x + a.y*b.y (f16 inputs, f32 accumulate)
__device__ __forceinline__ float dot2(unsigned int a, unsigned int b, float c) {
  return __builtin_amdgcn_fdot2(__builtin_bit_cast(half2_t, a),
                                __builtin_bit_cast(half2_t, b), c, false);
}
// pack 2 f32 -> packed f16 pair (RTZ)
__device__ __forceinline__ unsigned int pkh(float lo, float hi) {
  return __builtin_bit_cast(unsigned int, __builtin_amdgcn_cvt_pkrtz(lo, hi));
}
// ({b,a} >> 16) low 32 = (a.hi, b.lo) -> pair straddling two packed pairs
__device__ __forceinline__ unsigned int algn(unsigned int a, unsigned int b) {
  return __builtin_amdgcn_alignbit(a, b, 16);
}
__device__ __forceinline__ float lo16f(unsigned int p) {
  return (float)__builtin_bit_cast(half2_t, p)[0];
}
__device__ __forceinline__ float hi16f(unsigned int p) {
  return (float)__builtin_bit_cast(half2_t, p)[1];
}

// ---------------------------------------------------------------------------
// Kernel 1: pdf_mean[i][j] (112x112, 50KB -> L2-resident)
// ---------------------------------------------------------------------------
__global__ __launch_bounds__(256) void pdf_kernel(
    const float* __restrict__ loc,   // (L,2)
    const float* __restrict__ scal,  // (L,2)
    const float* __restrict__ pscal, // (1,)
    float* __restrict__ pdfm,        // (112*112,)
    int L) {
  int idx = blockIdx.x * 256 + threadIdx.x;
  if (idx >= WDIM * HDIM) return;
  int i = idx / HDIM;
  int j = idx - i * HDIM;
  float ps = pscal[0];
  float px = (float)i * ps;
  float py = (float)j * ps;
  const float LOG2PI = 1.8378770664093453f;  // log(2*pi)
  float s = 0.f;
  for (int l = 0; l < L; ++l) {
    float lx = loc[2 * l + 0], ly = loc[2 * l + 1];
    float sx = scal[2 * l + 0], sy = scal[2 * l + 1];
    float dx = (px - lx) / sx;
    float dy = (py - ly) / sy;
    float logp = -0.5f * (dx * dx + dy * dy) - (logf(sx) + logf(sy)) - LOG2PI;
    s += expf(logp);
  }
  pdfm[idx] = s / (float)L;
}

// ---------------------------------------------------------------------------
// Kernel 2: register-streaming fused conv->relu->conv->*pdf->+x, f16 dot2,
// 3-deep software-pipelined loads. No LDS/barriers. 8 groups of 32 lanes.
// Group: one (b,c) 28-row tile; lane owns 4 cols (lanes 28..31 idle/zero).
//
// 36 steps (n=0..35, s=s_base+n), rings period 6, chunk-of-6 unroll.
// Pipeline per step n (row s):
//   A issue load x row s+3 -> fbuf[u%3]      (consumed ~2.7 steps later,
//                                             ~1200cyc > 900cyc HBM latency)
//   B issue load pdf row g=s-4               (L1/L2-hot, consumed at F)
//   C pairs for row s from px ring + curA/curD (prepared at step n-1's G)
//   D conv1: row s -> v rows s-2..s+2 (vring; k=4 opens slot, bias folded)
//   E relu v row t=s-2 -> pack -> v-halo shuffles -> conv2 -> out rows t-2..t+2
//   F out row g: oring*pdf + unpack-f16(px ring residual), nontemporal store
//   G pack fbuf[(u+1)%3] (row s+1, loaded at step n-2) -> px slot (u+1)%6;
//     halo shuffles -> curA/curD
// ---------------------------------------------------------------------------
__global__ __launch_bounds__(256, 4) void fused_kernel(
    const float* __restrict__ x,
    const float* __restrict__ w1,  // (C,25)
    const float* __restrict__ b1,  // (C,)
    const float* __restrict__ w2,  // (C,25)
    const float* __restrict__ b2,  // (C,)
    const float* __restrict__ pdfm,
    float* __restrict__ out,
    int C) {
  const int tid = threadIdx.x;
  const int lane = tid & 31;
  const int group = tid >> 5;              // 0..7
  const int tile = blockIdx.x;             // 0..3
  const int c = blockIdx.y;                // channel (uniform per block)
  const int b = blockIdx.z * 8 + group;    // batch
  const int g0 = tile * TROWS;
  const int j0 = lane * 4;                 // output cols j0..j0+3

  const size_t plane = (size_t)(b * C + c) * (WDIM * HDIM);
  const float* xp = x + plane;
  float* op = out + plane;

  // Packed f16 weight pairs -> SGPRs via readfirstlane (uniform per block).
  unsigned int w1pa[5], w1pb[5], w1pc[5], w2pa[5], w2pb[5], w2pc[5];
#pragma unroll
  for (int r = 0; r < 5; ++r) {
    const float* wr = w1 + c * 25 + r * 5;
    w1pa[r] = __builtin_amdgcn_readfirstlane(pkh(wr[0], wr[1]));
    w1pb[r] = __builtin_amdgcn_readfirstlane(pkh(wr[2], wr[3]));
    w1pc[r] = __builtin_amdgcn_readfirstlane(pkh(wr[4], 0.f));
  }
#pragma unroll
  for (int r = 0; r < 5; ++r) {
    const float* wr = w2 + c * 25 + r * 5;
    w2pa[r] = __builtin_amdgcn_readfirstlane(pkh(wr[0], wr[1]));
    w2pb[r] = __builtin_amdgcn_readfirstlane(pkh(wr[2], wr[3]));
    w2pc[r] = __builtin_amdgcn_readfirstlane(pkh(wr[4], 0.f));
  }
  const float b1v = b1[c];
  const float b2v = b2[c];

  // Rings (statically indexed after unroll -> registers).
  unsigned int px01[6], px23[6];  // packed f16 x rows (also residual source)
  float vring[6][4];              // partial conv1 rows
  float oring[6][4];              // partial conv2 rows
#pragma unroll
  for (int r = 0; r < 6; ++r) {
    px01[r] = 0u; px23[r] = 0u;
#pragma unroll
    for (int q = 0; q < 4; ++q) { vring[r][q] = 0.f; oring[r][q] = 0.f; }
  }

  const bool lane_b = (lane < 28);
  const int s_base = g0 - 4;

  // Prologue: pack row s_base -> px[0] + halos; raw rows s_base+1 -> fbuf1,
  // s_base+2 -> fbuf2 (the loop's A fills s_base+3.. from step 0 onward).
  unsigned int curA, curD;
  float4 fbuf0 = make_float4(0.f, 0.f, 0.f, 0.f);
  float4 fbuf1 = make_float4(0.f, 0.f, 0.f, 0.f);
  float4 fbuf2 = make_float4(0.f, 0.f, 0.f, 0.f);
  {
    float4 t = make_float4(0.f, 0.f, 0.f, 0.f);
    if (s_base >= 0 && lane_b)
      t = *reinterpret_cast<const float4*>(xp + s_base * HDIM + j0);
    const unsigned int c01 = pkh(t.x, t.y);
    const unsigned int c23 = pkh(t.z, t.w);
    px01[0] = c01; px23[0] = c23;
    curA = __shfl_up(c23, 1, 32);
    if (lane == 0) curA = 0u;
    curD = __shfl_down(c01, 1, 32);
    const int s1 = s_base + 1;
    if (s1 >= 0 && lane_b)  // s1 < WDIM always
      fbuf1 = *reinterpret_cast<const float4*>(xp + s1 * HDIM + j0);
    const int s2 = s_base + 2;
    if (s2 >= 0 && lane_b)  // s2 < WDIM always
      fbuf2 = *reinterpret_cast<const float4*>(xp + s2 * HDIM + j0);
  }

  for (int chunk = 0; chunk < 6; ++chunk) {
#pragma unroll
    for (int u = 0; u < 6; ++u) {
      const int s = s_base + chunk * 6 + u;  // current x row
      const int g = s - 4;                   // output row this step

      // ---- A. issue x load row s+3 -> fbuf[u%3] (consumed 2.7 steps on) ----
      {
        const int sp = s + 3;
        float4 t = make_float4(0.f, 0.f, 0.f, 0.f);
        if (sp >= 0 && sp < WDIM && lane_b)
          t = *reinterpret_cast<const float4*>(xp + sp * HDIM + j0);
        if ((u % 3) == 0) fbuf0 = t;
        else if ((u % 3) == 1) fbuf1 = t;
        else fbuf2 = t;
      }

      // ---- B. issue pdf load for row g (consumed at F) ----
      float4 pv = make_float4(0.f, 0.f, 0.f, 0.f);
      if (g >= g0 && lane_b)  // g < g0+TROWS always
        pv = *reinterpret_cast<const float4*>(pdfm + g * HDIM + j0);

      // ---- C. tap pairs for row s (from regs prepared at step n-1) ----
      const unsigned int a01 = px01[u], a23 = px23[u];
      const unsigned int o1 = algn(a01, curA);   // (x[j0-1], x[j0])
      const unsigned int o2 = algn(a23, a01);    // (x[j0+1], x[j0+2])
      const unsigned int o3 = algn(curD, a23);   // (x[j0+3], x[j0+4])
      const unsigned int o4 = curD >> 16;        // (x[j0+5], 0)
      const unsigned int p1[4] = {curA, o1, a01, o2};
      const unsigned int p2[4] = {a01, o2, a23, o3};
      const unsigned int p3[4] = {a23, o3, curD, o4};

      // ---- D. conv1: row s -> v rows s-2..s+2 (k=4 opens slot, bias fold) ----
#pragma unroll
      for (int k = 4; k >= 0; --k) {
        const int slot = (u + 4 + k) % 6;  // v row t = s-2+k
        const int dr = 4 - k;              // weight row: s = t-2+dr
#pragma unroll
        for (int cc = 0; cc < 4; ++cc) {
          float acc = (k == 4) ? b1v : vring[slot][cc];
          acc = dot2(w1pa[dr], p1[cc], acc);
          acc = dot2(w1pb[dr], p2[cc], acc);
          vring[slot][cc] = dot2(w1pc[dr], p3[cc], acc);
        }
      }

      // ---- E. finalize v row t=s-2: relu, pack, halo, conv2 ----
      const int t_ = s - 2;
      const bool tval = (t_ >= 0) && (t_ < WDIM);
      const int fs = (u + 4) % 6;
      const float vc0 = (tval && lane_b) ? fmaxf(vring[fs][0], 0.f) : 0.f;
      const float vc1 = (tval && lane_b) ? fmaxf(vring[fs][1], 0.f) : 0.f;
      const float vc2 = (tval && lane_b) ? fmaxf(vring[fs][2], 0.f) : 0.f;
      const float vc3 = (tval && lane_b) ? fmaxf(vring[fs][3], 0.f) : 0.f;
      const unsigned int V01 = pkh(vc0, vc1);
      const unsigned int V23 = pkh(vc2, vc3);
      unsigned int vA = __shfl_up(V23, 1, 32);
      if (lane == 0) vA = 0u;
      const unsigned int vD = __shfl_down(V01, 1, 32);  // lane28 vc==0 pad ok
      const unsigned int q1 = algn(V01, vA);
      const unsigned int q2 = algn(V23, V01);
      const unsigned int q3 = algn(vD, V23);
      const unsigned int q4 = vD >> 16;
      const unsigned int r1[4] = {vA, q1, V01, q2};
      const unsigned int r2[4] = {V01, q2, V23, q3};
      const unsigned int r3[4] = {V23, q3, vD, q4};
#pragma unroll
      for (int k = 4; k >= 0; --k) {
        const int slot = (u + 2 + k) % 6;  // out row gk = s-4+k
        const int dr = 4 - k;              // weight row: t = gk-2+dr
#pragma unroll
        for (int cc = 0; cc < 4; ++cc) {
          float acc = (k == 4) ? b2v : oring[slot][cc];
          acc = dot2(w2pa[dr], r1[cc], acc);
          acc = dot2(w2pb[dr], r2[cc], acc);
          oring[slot][cc] = dot2(w2pc[dr], r3[cc], acc);
        }
      }

      // ---- F. out row g: *pdf + residual; nontemporal store (no re-read) ----
      if (g >= g0 && lane_b) {
        const int os = (u + 2) % 6;
        const unsigned int rx01 = px01[os], rx23 = px23[os];
        fvec4 o;
        o.x = fmaf(oring[os][0], pv.x, lo16f(rx01));
        o.y = fmaf(oring[os][1], pv.y, hi16f(rx01));
        o.z = fmaf(oring[os][2], pv.z, lo16f(rx23));
        o.w = fmaf(oring[os][3], pv.w, hi16f(rx23));
        __builtin_nontemporal_store(o, reinterpret_cast<fvec4*>(op + g * HDIM + j0));
      }

      // ---- G. pack row s+1 (loaded at step n-2) -> px slot (u+1)%6 ----
      {
        const float4 f = (((u + 1) % 3) == 0) ? fbuf0
                       : ((((u + 1) % 3) == 1) ? fbuf1 : fbuf2);
        const unsigned int n01 = pkh(f.x, f.y);
        const unsigned int n23 = pkh(f.z, f.w);
        px01[(u + 1) % 6] = n01;
        px23[(u + 1) % 6] = n23;
        unsigned int nA = __shfl_up(n23, 1, 32);
        if (lane == 0) nA = 0u;
        curA = nA;
        curD = __shfl_down(n01, 1, 32);
      }
    }
  }
}

extern "C" void kernel_launch(void* const* d_in, const int* in_sizes, int n_in,
                              void* d_out, int out_size, void* d_ws, size_t ws_size,
                              hipStream_t stream) {
  const float* x    = (const float*)d_in[0];
  const float* w1   = (const float*)d_in[1];
  const float* b1   = (const float*)d_in[2];
  const float* w2   = (const float*)d_in[3];
  const float* b2   = (const float*)d_in[4];
  const float* loc  = (const float*)d_in[5];
  const float* scal = (const float*)d_in[6];
  const float* ps   = (const float*)d_in[7];
  float* out = (float*)d_out;
  float* pdfm = (float*)d_ws;  // 112*112 floats = 50 KB scratch

  const int C = in_sizes[2];                     // 256
  const int L = in_sizes[5] / 2;                 // 8

  hipLaunchKernelGGL(pdf_kernel, dim3((WDIM * HDIM + 255) / 256), dim3(256), 0,
                     stream, loc, scal, ps, pdfm, L);
  // grid: (4 row-tiles, channel, batch-octet); block = 8 batches x 32 lanes.
  dim3 grid(4, C, 2);
  hipLaunchKernelGGL(fused_kernel, grid, dim3(256), 0, stream, x, w1, b1, w2,
                     b2, pdfm, out, C);
}